// Round 5
// baseline (336.376 us; speedup 1.0000x reference)
//
#include <hip/hip_runtime.h>

// GCN forward, CSR-gather, bf16 pre-scaled messages, half-wave edge pairing.
// x1 == x2 (dropout identity) => single branch, summed lin_W halves.
// h1s[i] = inv[i] * (x @ W1)[i]        (bf16)
// agg1[i] = relu( inv[i]*(sum_{s in N(i)} h1s[s] + h1s[i]) + b1 )   (fp32)
// h2s[i] = inv[i] * (agg1 @ W2)[i]     (bf16)
// z[i]   = inv[i]*(sum h2s[s] + h2s[i]) + b2
// out    = log_softmax(z @ (linW_top+linW_bot) + linb)

#define CIN  128
#define CHID 128
#define COUT 64
#define SB   256   // scan block size

static __device__ __forceinline__ unsigned short f2bf(float f) {
    unsigned int u = __float_as_uint(f);
    unsigned int r = (u + 0x7fffu + ((u >> 16) & 1u)) >> 16;  // RNE
    return (unsigned short)r;
}
static __device__ __forceinline__ float bf_lo(unsigned int u) {
    return __uint_as_float(u << 16);
}
static __device__ __forceinline__ float bf_hi(unsigned int u) {
    return __uint_as_float(u & 0xffff0000u);
}
static __device__ __forceinline__ float readlane_f(float v, int lane) {
    return __uint_as_float(__builtin_amdgcn_readlane(__float_as_uint(v), lane));
}

// ---------------- degree ----------------
__global__ void deg_count_kernel(const int* __restrict__ dst, int* __restrict__ cnt, int E) {
    int e = blockIdx.x * blockDim.x + threadIdx.x;
    if (e < E) atomicAdd(&cnt[dst[e]], 1);
}

// ---------------- hierarchical scan: pass 1, per-block sums ----------------
__global__ __launch_bounds__(SB) void bsum_kernel(const int* __restrict__ cnt,
                                                  int* __restrict__ bsum, int n) {
    __shared__ int s[SB];
    int t = threadIdx.x, g = blockIdx.x * SB + t;
    s[t] = (g < n) ? cnt[g] : 0;
    __syncthreads();
    for (int off = SB / 2; off >= 1; off >>= 1) {
        if (t < off) s[t] += s[t + off];
        __syncthreads();
    }
    if (t == 0) bsum[blockIdx.x] = s[0];
}

// ---------------- pass 2: 1-block exclusive scan of block sums ----------------
__global__ __launch_bounds__(SB) void bscan_kernel(int* __restrict__ bsum, int nb) {
    __shared__ int s[SB];
    int t = threadIdx.x;
    int v = (t < nb) ? bsum[t] : 0;
    s[t] = v;
    __syncthreads();
    for (int off = 1; off < SB; off <<= 1) {
        int u = (t >= off) ? s[t - off] : 0;
        __syncthreads();
        s[t] += u;
        __syncthreads();
    }
    if (t < nb) bsum[t] = s[t] - v;  // exclusive
}

// ---------------- pass 3: per-block rescan + scatter rowptr/cursor, fused inv ----------------
__global__ __launch_bounds__(SB) void scan_scatter_kernel(const int* __restrict__ cnt,
                                                          const int* __restrict__ bsum,
                                                          int* __restrict__ rowptr,
                                                          int* __restrict__ cursor,
                                                          float* __restrict__ inv,
                                                          int n, int E) {
    __shared__ int s[SB];
    int t = threadIdx.x, g = blockIdx.x * SB + t;
    int c = (g < n) ? cnt[g] : 0;
    s[t] = c;
    __syncthreads();
    for (int off = 1; off < SB; off <<= 1) {
        int u = (t >= off) ? s[t - off] : 0;
        __syncthreads();
        s[t] += u;
        __syncthreads();
    }
    if (g < n) {
        int ex = bsum[blockIdx.x] + s[t] - c;
        rowptr[g] = ex;
        cursor[g] = ex;
        inv[g] = rsqrtf((float)(c + 1));  // +1: self-loop
    }
    if (g == 0) rowptr[n] = E;
}

// ---------------- bucket-fill ----------------
__global__ void fill_kernel(const int* __restrict__ src, const int* __restrict__ dst,
                            int* __restrict__ cursor, int* __restrict__ ebuf, int E) {
    int e = blockIdx.x * blockDim.x + threadIdx.x;
    if (e >= E) return;
    int pos = atomicAdd(&cursor[dst[e]], 1);
    ebuf[pos] = src[e];
}

// ---------------- GEMM: H[i] = inv[i] * (X @ W)[i], bf16 output ----------------
// NOUT threads, R rows/block; w-outer r-inner with on-demand ds_read_b128.
template <int K, int NOUT, int R>
__global__ void gemm_rows_bf16(const float* __restrict__ X, const float* __restrict__ W,
                               const float* __restrict__ inv, unsigned short* __restrict__ H,
                               int n) {
    __shared__ float xs[R][K];
    int j = threadIdx.x;
    int n0 = blockIdx.x * R;
    constexpr int NF4 = R * K / 4;
    const float4* X4 = (const float4*)(X + (size_t)n0 * K);
    for (int t = j; t < NF4; t += NOUT) {
        int r = t / (K / 4);
        float4 v = (n0 + r < n) ? X4[t] : make_float4(0.f, 0.f, 0.f, 0.f);
        ((float4*)xs)[t] = v;
    }
    __syncthreads();
    float acc[R];
#pragma unroll
    for (int r = 0; r < R; ++r) acc[r] = 0.f;
    for (int k4 = 0; k4 < K / 4; ++k4) {
        float w0 = W[(k4 * 4 + 0) * NOUT + j];
        float w1 = W[(k4 * 4 + 1) * NOUT + j];
        float w2 = W[(k4 * 4 + 2) * NOUT + j];
        float w3 = W[(k4 * 4 + 3) * NOUT + j];
#pragma unroll
        for (int r = 0; r < R; ++r) {
            float4 xv = ((const float4*)xs[r])[k4];
            acc[r] = fmaf(xv.x, w0, acc[r]);
            acc[r] = fmaf(xv.y, w1, acc[r]);
            acc[r] = fmaf(xv.z, w2, acc[r]);
            acc[r] = fmaf(xv.w, w3, acc[r]);
        }
    }
#pragma unroll
    for (int r = 0; r < R; ++r)
        if (n0 + r < n) H[(size_t)(n0 + r) * NOUT + j] = f2bf(acc[r] * inv[n0 + r]);
}

// ---------------- layer-1 aggregate (C=128 bf16): wave/node, 2 edges/iter ------
// Half-wave h (lanes 0-31 / 32-63) each gathers one edge row; uint2 = 4 ch/lane.
__global__ void agg1_kernel(const uint2* __restrict__ H2, const int* __restrict__ ebuf,
                            const int* __restrict__ rowptr, const float* __restrict__ inv,
                            const float* __restrict__ bias, float* __restrict__ outp, int n) {
    int node = __builtin_amdgcn_readfirstlane(blockIdx.x * 4 + (threadIdx.x >> 6));
    int lane = threadIdx.x & 63;
    int half = lane >> 5;
    int l32  = lane & 31;
    if (node >= n) return;
    int beg = rowptr[node], end = rowptr[node + 1];  // uniform -> s_load
    float a0 = 0.f, a1 = 0.f, a2 = 0.f, a3 = 0.f;
    int k = beg;
#pragma unroll 2
    for (; k + 2 <= end; k += 2) {
        int s0 = ebuf[k];          // uniform -> s_load
        int s1 = ebuf[k + 1];
        int s  = half ? s1 : s0;   // v_cndmask
        uint2 u = H2[(size_t)s * 32 + l32];
        a0 += bf_lo(u.x); a1 += bf_hi(u.x);
        a2 += bf_lo(u.y); a3 += bf_hi(u.y);
    }
    if (k < end && half == 0) {    // odd tail: lanes 0-31 only
        int s = ebuf[k];
        uint2 u = H2[(size_t)s * 32 + l32];
        a0 += bf_lo(u.x); a1 += bf_hi(u.x);
        a2 += bf_lo(u.y); a3 += bf_hi(u.y);
    }
    // combine halves (both halves end up with full sums)
    a0 += __shfl_xor(a0, 32, 64);
    a1 += __shfl_xor(a1, 32, 64);
    a2 += __shfl_xor(a2, 32, 64);
    a3 += __shfl_xor(a3, 32, 64);
    // self-loop
    {
        uint2 u = H2[(size_t)node * 32 + l32];
        a0 += bf_lo(u.x); a1 += bf_hi(u.x);
        a2 += bf_lo(u.y); a3 += bf_hi(u.y);
    }
    if (half == 0) {
        float wd = inv[node];
        float4 bv = ((const float4*)bias)[l32];
        float4 o;
        o.x = fmaxf(fmaf(wd, a0, bv.x), 0.f);
        o.y = fmaxf(fmaf(wd, a1, bv.y), 0.f);
        o.z = fmaxf(fmaf(wd, a2, bv.z), 0.f);
        o.w = fmaxf(fmaf(wd, a3, bv.w), 0.f);
        ((float4*)outp)[(size_t)node * 32 + l32] = o;
    }
}

// ---------------- Wpair: k-interleaved (linW_top + linW_bot) ----------------
// Wpair[k2][j] = float2( Wsum[2k2][j], Wsum[2k2+1][j] ), flat float layout.
__global__ void wsum_kernel(const float* __restrict__ linW, float* __restrict__ Wpair) {
    int i = blockIdx.x * blockDim.x + threadIdx.x;   // over 2*COUT*COUT/… = 4096
    if (i >= 2 * COUT * COUT / 2) return;            // 4096 entries
    int kk = i >> 6, j = i & 63;                     // kk in [0,64)
    float v = linW[kk * COUT + j] + linW[COUT * COUT + kk * COUT + j];
    Wpair[(size_t)(kk >> 1) * 128 + j * 2 + (kk & 1)] = v;
}

// ---------------- layer-2 aggregate + fused concat-linear + log_softmax --------
// Half-wave edge pairing (uint = 2 ch/lane), readlane-based matvec with Wpair.
__global__ void agg2_final_kernel(const unsigned int* __restrict__ H32,
                                  const int* __restrict__ ebuf, const int* __restrict__ rowptr,
                                  const float* __restrict__ inv, const float* __restrict__ bias,
                                  const float2* __restrict__ Wpair, const float* __restrict__ linb,
                                  float* __restrict__ outp, int n) {
    int node = __builtin_amdgcn_readfirstlane(blockIdx.x * 4 + (threadIdx.x >> 6));
    int lane = threadIdx.x & 63;
    int half = lane >> 5;
    int l32  = lane & 31;
    if (node >= n) return;
    int beg = rowptr[node], end = rowptr[node + 1];  // uniform -> s_load
    float ax = 0.f, ay = 0.f;
    int k = beg;
#pragma unroll 2
    for (; k + 2 <= end; k += 2) {
        int s0 = ebuf[k];
        int s1 = ebuf[k + 1];
        int s  = half ? s1 : s0;
        unsigned int u = H32[(size_t)s * 32 + l32];
        ax += bf_lo(u); ay += bf_hi(u);
    }
    if (k < end && half == 0) {
        int s = ebuf[k];
        unsigned int u = H32[(size_t)s * 32 + l32];
        ax += bf_lo(u); ay += bf_hi(u);
    }
    ax += __shfl_xor(ax, 32, 64);
    ay += __shfl_xor(ay, 32, 64);
    {   // self-loop
        unsigned int u = H32[(size_t)node * 32 + l32];
        ax += bf_lo(u); ay += bf_hi(u);
    }
    // z pair (channels 2*l32, 2*l32+1), identical on both halves
    float wd = inv[node];
    float2 bv = ((const float2*)bias)[l32];
    float zx = fmaf(wd, ax, bv.x);
    float zy = fmaf(wd, ay, bv.y);
    // fused concat-linear: fo_j = linb_j + sum_k2 z2(k2) . Wpair[k2][j]
    float fo = linb[lane];
#pragma unroll
    for (int k2 = 0; k2 < COUT / 2; ++k2) {
        float bzx = readlane_f(zx, k2);      // sgpr broadcast
        float bzy = readlane_f(zy, k2);
        float2 wp = Wpair[(size_t)k2 * 64 + lane];
        fo = fmaf(bzx, wp.x, fo);
        fo = fmaf(bzy, wp.y, fo);
    }
    // log_softmax across the wave
    float mx = fo;
#pragma unroll
    for (int off = 32; off >= 1; off >>= 1) mx = fmaxf(mx, __shfl_xor(mx, off, 64));
    float ex = expf(fo - mx);
    float s = ex;
#pragma unroll
    for (int off = 32; off >= 1; off >>= 1) s += __shfl_xor(s, off, 64);
    outp[(size_t)node * COUT + lane] = fo - mx - logf(s);
}

static inline size_t align16(size_t x) { return (x + 15) & ~(size_t)15; }

extern "C" void kernel_launch(void* const* d_in, const int* in_sizes, int n_in,
                              void* d_out, int out_size, void* d_ws, size_t ws_size,
                              hipStream_t stream) {
    const float* x    = (const float*)d_in[0];
    const int*   eidx = (const int*)d_in[1];
    const float* W1   = (const float*)d_in[2];
    const float* b1   = (const float*)d_in[3];
    const float* W2   = (const float*)d_in[4];
    const float* b2   = (const float*)d_in[5];
    const float* linW = (const float*)d_in[6];
    const float* linb = (const float*)d_in[7];
    float* out = (float*)d_out;

    const int n = in_sizes[0] / CIN;   // 50000
    const int E = in_sizes[1] / 2;     // 800000
    const int* src = eidx;
    const int* dst = eidx + E;
    const int NB = (n + SB - 1) / SB;

    // ---- workspace carve-up
    char* ws = (char*)d_ws;
    size_t off = 0;
    int*   cnt    = (int*)(ws + off);   off = align16(off + (size_t)n * 4);
    int*   rowptr = (int*)(ws + off);   off = align16(off + (size_t)(n + 1) * 4);
    int*   cursor = (int*)(ws + off);   off = align16(off + (size_t)n * 4);
    float* inv    = (float*)(ws + off); off = align16(off + (size_t)n * 4);
    int*   bsum   = (int*)(ws + off);   off = align16(off + (size_t)SB * 4);
    float* Wpair  = (float*)(ws + off); off = align16(off + (size_t)COUT * COUT * 4);
    int*   ebuf   = (int*)(ws + off);   off = align16(off + (size_t)E * 4);
    unsigned short* h1s = (unsigned short*)(ws + off); off = align16(off + (size_t)n * CHID * 2);
    float* agg1   = (float*)(ws + off); off = align16(off + (size_t)n * CHID * 4);
    unsigned short* h2s = (unsigned short*)(ws + off); off = align16(off + (size_t)n * COUT * 2);

    hipMemsetAsync(cnt, 0, (size_t)n * 4, stream);

    // ---- CSR build (hierarchical scan)
    deg_count_kernel<<<(E + 255) / 256, 256, 0, stream>>>(dst, cnt, E);
    bsum_kernel<<<NB, SB, 0, stream>>>(cnt, bsum, n);
    bscan_kernel<<<1, SB, 0, stream>>>(bsum, NB);
    scan_scatter_kernel<<<NB, SB, 0, stream>>>(cnt, bsum, rowptr, cursor, inv, n, E);
    fill_kernel<<<(E + 255) / 256, 256, 0, stream>>>(src, dst, cursor, ebuf, E);
    wsum_kernel<<<(COUT * COUT + 255) / 256, 256, 0, stream>>>(linW, Wpair);

    // ---- layer 1
    gemm_rows_bf16<CIN, CHID, 16><<<(n + 15) / 16, CHID, 0, stream>>>(x, W1, inv, h1s, n);
    agg1_kernel<<<(n + 3) / 4, 256, 0, stream>>>((const uint2*)h1s, ebuf, rowptr, inv, b1, agg1, n);

    // ---- layer 2 + fused final
    gemm_rows_bf16<CHID, COUT, 16><<<(n + 15) / 16, COUT, 0, stream>>>(agg1, W2, inv, h2s, n);
    agg2_final_kernel<<<(n + 3) / 4, 256, 0, stream>>>((const unsigned int*)h2s, ebuf, rowptr,
                                                       inv, b2, (const float2*)Wpair, linb, out, n);
}

// Round 6
// 312.497 us; speedup vs baseline: 1.0764x; 1.0764x over previous
//
#include <hip/hip_runtime.h>

// GCN forward, CSR-gather, bf16 pre-scaled messages, scalar edge walk.
// x1 == x2 (dropout identity) => single branch.
// Output projection folded into layer-2 weights (aggregation is linear):
//   W2' = W2 @ (linW_top + linW_bot),  b' = b2 @ (linW_top+linW_bot) + linb
//   h1s[i]  = inv[i] * (x @ W1)[i]                  (bf16)
//   agg1[i] = relu( inv[i]*(sum_{N+(i)} h1s[s]) + b1 )   (fp32)
//   h2p[i]  = inv[i] * (agg1 @ W2')[i]              (bf16)
//   fo[i]   = inv[i]*(sum_{N+(i)} h2p[s]) + b'
//   out     = log_softmax(fo)

#define CIN  128
#define CHID 128
#define COUT 64
#define SB   256   // scan block size

static __device__ __forceinline__ unsigned short f2bf(float f) {
    unsigned int u = __float_as_uint(f);
    unsigned int r = (u + 0x7fffu + ((u >> 16) & 1u)) >> 16;  // RNE
    return (unsigned short)r;
}
static __device__ __forceinline__ float bf2f(unsigned short v) {
    return __uint_as_float(((unsigned int)v) << 16);
}

// ---------------- degree ----------------
__global__ void deg_count_kernel(const int* __restrict__ dst, int* __restrict__ cnt, int E) {
    int e = blockIdx.x * blockDim.x + threadIdx.x;
    if (e < E) atomicAdd(&cnt[dst[e]], 1);
}

// ---------------- hierarchical scan: pass 1, per-block sums ----------------
__global__ __launch_bounds__(SB) void bsum_kernel(const int* __restrict__ cnt,
                                                  int* __restrict__ bsum, int n) {
    __shared__ int s[SB];
    int t = threadIdx.x, g = blockIdx.x * SB + t;
    s[t] = (g < n) ? cnt[g] : 0;
    __syncthreads();
    for (int off = SB / 2; off >= 1; off >>= 1) {
        if (t < off) s[t] += s[t + off];
        __syncthreads();
    }
    if (t == 0) bsum[blockIdx.x] = s[0];
}

// ---------------- pass 2: 1-block exclusive scan of block sums ----------------
__global__ __launch_bounds__(SB) void bscan_kernel(int* __restrict__ bsum, int nb) {
    __shared__ int s[SB];
    int t = threadIdx.x;
    int v = (t < nb) ? bsum[t] : 0;
    s[t] = v;
    __syncthreads();
    for (int off = 1; off < SB; off <<= 1) {
        int u = (t >= off) ? s[t - off] : 0;
        __syncthreads();
        s[t] += u;
        __syncthreads();
    }
    if (t < nb) bsum[t] = s[t] - v;  // exclusive
}

// ---------------- pass 3: per-block rescan + scatter rowptr/cursor, fused inv ----------------
__global__ __launch_bounds__(SB) void scan_scatter_kernel(const int* __restrict__ cnt,
                                                          const int* __restrict__ bsum,
                                                          int* __restrict__ rowptr,
                                                          int* __restrict__ cursor,
                                                          float* __restrict__ inv,
                                                          int n, int E) {
    __shared__ int s[SB];
    int t = threadIdx.x, g = blockIdx.x * SB + t;
    int c = (g < n) ? cnt[g] : 0;
    s[t] = c;
    __syncthreads();
    for (int off = 1; off < SB; off <<= 1) {
        int u = (t >= off) ? s[t - off] : 0;
        __syncthreads();
        s[t] += u;
        __syncthreads();
    }
    if (g < n) {
        int ex = bsum[blockIdx.x] + s[t] - c;
        rowptr[g] = ex;
        cursor[g] = ex;
        inv[g] = rsqrtf((float)(c + 1));  // +1: self-loop
    }
    if (g == 0) rowptr[n] = E;
}

// ---------------- bucket-fill ----------------
__global__ void fill_kernel(const int* __restrict__ src, const int* __restrict__ dst,
                            int* __restrict__ cursor, int* __restrict__ ebuf, int E) {
    int e = blockIdx.x * blockDim.x + threadIdx.x;
    if (e >= E) return;
    int pos = atomicAdd(&cursor[dst[e]], 1);
    ebuf[pos] = src[e];
}

// ---------------- W2' = W2 @ Wsum ; b' = b2 @ Wsum + linb ----------------
// Wsum[k][j] = linW[k][j] + linW[k+64][j]. Block r<128: row r of W2'; r==128: b'.
__global__ __launch_bounds__(COUT) void w2p_kernel(const float* __restrict__ W2,
                                                   const float* __restrict__ b2,
                                                   const float* __restrict__ linW,
                                                   const float* __restrict__ linb,
                                                   float* __restrict__ W2p,
                                                   float* __restrict__ bp) {
    int r = blockIdx.x;   // 0..128
    int j = threadIdx.x;  // 0..63
    float acc = 0.f;
    if (r < CHID) {
#pragma unroll 8
        for (int k = 0; k < COUT; ++k) {
            float ws = linW[k * COUT + j] + linW[(k + COUT) * COUT + j];
            acc = fmaf(W2[r * COUT + k], ws, acc);
        }
        W2p[r * COUT + j] = acc;
    } else {
#pragma unroll 8
        for (int k = 0; k < COUT; ++k) {
            float ws = linW[k * COUT + j] + linW[(k + COUT) * COUT + j];
            acc = fmaf(b2[k], ws, acc);
        }
        bp[j] = acc + linb[j];
    }
}

// ---------------- GEMM: H[i] = inv[i] * (X @ W)[i], bf16 output ----------------
template <int K, int NOUT, int R>
__global__ void gemm_rows_bf16(const float* __restrict__ X, const float* __restrict__ W,
                               const float* __restrict__ inv, unsigned short* __restrict__ H,
                               int n) {
    __shared__ float xs[R][K];
    int j = threadIdx.x;
    int n0 = blockIdx.x * R;
    constexpr int NF4 = R * K / 4;
    const float4* X4 = (const float4*)(X + (size_t)n0 * K);
    for (int t = j; t < NF4; t += NOUT) {
        int r = t / (K / 4);
        float4 v = (n0 + r < n) ? X4[t] : make_float4(0.f, 0.f, 0.f, 0.f);
        ((float4*)xs)[t] = v;
    }
    __syncthreads();
    float acc[R];
#pragma unroll
    for (int r = 0; r < R; ++r) acc[r] = 0.f;
    for (int k4 = 0; k4 < K / 4; ++k4) {
        float w0 = W[(k4 * 4 + 0) * NOUT + j];
        float w1 = W[(k4 * 4 + 1) * NOUT + j];
        float w2 = W[(k4 * 4 + 2) * NOUT + j];
        float w3 = W[(k4 * 4 + 3) * NOUT + j];
#pragma unroll
        for (int r = 0; r < R; ++r) {
            float4 xv = ((const float4*)xs[r])[k4];
            acc[r] = fmaf(xv.x, w0, acc[r]);
            acc[r] = fmaf(xv.y, w1, acc[r]);
            acc[r] = fmaf(xv.z, w2, acc[r]);
            acc[r] = fmaf(xv.w, w3, acc[r]);
        }
    }
#pragma unroll
    for (int r = 0; r < R; ++r)
        if (n0 + r < n) H[(size_t)(n0 + r) * NOUT + j] = f2bf(acc[r] * inv[n0 + r]);
}

// ---------------- layer-1 aggregate (C=128 bf16): wave/node, scalar edge walk ----
__global__ void agg1_kernel(const unsigned int* __restrict__ Hs, const int* __restrict__ ebuf,
                            const int* __restrict__ rowptr, const float* __restrict__ inv,
                            const float* __restrict__ bias, float* __restrict__ outp, int n) {
    int node = __builtin_amdgcn_readfirstlane(blockIdx.x * 4 + (threadIdx.x >> 6));
    int lane = threadIdx.x & 63;
    if (node >= n) return;
    int beg = rowptr[node], end = rowptr[node + 1];  // uniform addr -> s_load
    float ax = 0.f, ay = 0.f;
#pragma unroll 4
    for (int k = beg; k < end; ++k) {
        int s = ebuf[k];                             // uniform addr -> s_load
        unsigned int u = Hs[(size_t)s * 64 + lane];  // sgpr base + lane offset
        ax += __uint_as_float(u << 16);
        ay += __uint_as_float(u & 0xffff0000u);
    }
    {   // self-loop term
        unsigned int u = Hs[(size_t)node * 64 + lane];
        ax += __uint_as_float(u << 16);
        ay += __uint_as_float(u & 0xffff0000u);
    }
    float wd = inv[node];
    float2 bv = ((const float2*)bias)[lane];
    float ox = fmaxf(fmaf(wd, ax, bv.x), 0.f);
    float oy = fmaxf(fmaf(wd, ay, bv.y), 0.f);
    ((float2*)outp)[(size_t)node * 64 + lane] = make_float2(ox, oy);
}

// ---------------- layer-2 aggregate + bias + log_softmax (projection pre-folded) ----
__global__ void agg2_final_kernel(const unsigned short* __restrict__ Hs,
                                  const int* __restrict__ ebuf, const int* __restrict__ rowptr,
                                  const float* __restrict__ inv, const float* __restrict__ bp,
                                  float* __restrict__ outp, int n) {
    int node = __builtin_amdgcn_readfirstlane(blockIdx.x * 4 + (threadIdx.x >> 6));
    int lane = threadIdx.x & 63;
    if (node >= n) return;
    int beg = rowptr[node], end = rowptr[node + 1];  // uniform -> s_load
    float acc = 0.f;
#pragma unroll 4
    for (int k = beg; k < end; ++k) {
        int s = ebuf[k];                             // uniform -> s_load
        acc += bf2f(Hs[(size_t)s * 64 + lane]);
    }
    acc += bf2f(Hs[(size_t)node * 64 + lane]);       // self-loop
    float fo = fmaf(inv[node], acc, bp[lane]);
    // log_softmax across the wave
    float mx = fo;
#pragma unroll
    for (int off = 32; off >= 1; off >>= 1) mx = fmaxf(mx, __shfl_xor(mx, off, 64));
    float ex = expf(fo - mx);
    float s = ex;
#pragma unroll
    for (int off = 32; off >= 1; off >>= 1) s += __shfl_xor(s, off, 64);
    outp[(size_t)node * COUT + lane] = fo - mx - logf(s);
}

static inline size_t align16(size_t x) { return (x + 15) & ~(size_t)15; }

extern "C" void kernel_launch(void* const* d_in, const int* in_sizes, int n_in,
                              void* d_out, int out_size, void* d_ws, size_t ws_size,
                              hipStream_t stream) {
    const float* x    = (const float*)d_in[0];
    const int*   eidx = (const int*)d_in[1];
    const float* W1   = (const float*)d_in[2];
    const float* b1   = (const float*)d_in[3];
    const float* W2   = (const float*)d_in[4];
    const float* b2   = (const float*)d_in[5];
    const float* linW = (const float*)d_in[6];
    const float* linb = (const float*)d_in[7];
    float* out = (float*)d_out;

    const int n = in_sizes[0] / CIN;   // 50000
    const int E = in_sizes[1] / 2;     // 800000
    const int* src = eidx;
    const int* dst = eidx + E;
    const int NB = (n + SB - 1) / SB;

    // ---- workspace carve-up
    char* ws = (char*)d_ws;
    size_t off = 0;
    int*   cnt    = (int*)(ws + off);   off = align16(off + (size_t)n * 4);
    int*   rowptr = (int*)(ws + off);   off = align16(off + (size_t)(n + 1) * 4);
    int*   cursor = (int*)(ws + off);   off = align16(off + (size_t)n * 4);
    float* inv    = (float*)(ws + off); off = align16(off + (size_t)n * 4);
    int*   bsum   = (int*)(ws + off);   off = align16(off + (size_t)SB * 4);
    float* W2p    = (float*)(ws + off); off = align16(off + (size_t)CHID * COUT * 4);
    float* bp     = (float*)(ws + off); off = align16(off + (size_t)COUT * 4);
    int*   ebuf   = (int*)(ws + off);   off = align16(off + (size_t)E * 4);
    unsigned short* h1s = (unsigned short*)(ws + off); off = align16(off + (size_t)n * CHID * 2);
    float* agg1   = (float*)(ws + off); off = align16(off + (size_t)n * CHID * 4);
    unsigned short* h2p = (unsigned short*)(ws + off); off = align16(off + (size_t)n * COUT * 2);

    hipMemsetAsync(cnt, 0, (size_t)n * 4, stream);

    // ---- CSR build (hierarchical scan) + weight folding
    deg_count_kernel<<<(E + 255) / 256, 256, 0, stream>>>(dst, cnt, E);
    bsum_kernel<<<NB, SB, 0, stream>>>(cnt, bsum, n);
    bscan_kernel<<<1, SB, 0, stream>>>(bsum, NB);
    scan_scatter_kernel<<<NB, SB, 0, stream>>>(cnt, bsum, rowptr, cursor, inv, n, E);
    fill_kernel<<<(E + 255) / 256, 256, 0, stream>>>(src, dst, cursor, ebuf, E);
    w2p_kernel<<<CHID + 1, COUT, 0, stream>>>(W2, b2, linW, linb, W2p, bp);

    // ---- layer 1
    gemm_rows_bf16<CIN, CHID, 16><<<(n + 15) / 16, CHID, 0, stream>>>(x, W1, inv, h1s, n);
    agg1_kernel<<<(n + 3) / 4, 256, 0, stream>>>((const unsigned int*)h1s, ebuf, rowptr, inv, b1, agg1, n);

    // ---- layer 2 (projection pre-folded into W2p) + final
    gemm_rows_bf16<CHID, COUT, 16><<<(n + 15) / 16, COUT, 0, stream>>>(agg1, W2p, inv, h2p, n);
    agg2_final_kernel<<<(n + 3) / 4, 256, 0, stream>>>(h2p, ebuf, rowptr, inv, bp, out, n);
}

// Round 7
// 262.646 us; speedup vs baseline: 1.2807x; 1.1898x over previous
//
#include <hip/hip_runtime.h>

// GCN forward, CSR-gather via 2-pass bucket sort (region-exclusive writers),
// bf16 pre-scaled messages, scalar edge walk, projection folded into layer 2.
// x1 == x2 (dropout identity) => single branch.
//   W2' = W2 @ (linW_top + linW_bot),  b' = b2 @ (linW_top+linW_bot) + linb
//   h1s[i]  = inv[i] * (x @ W1)[i]                  (bf16)
//   agg1[i] = relu( inv[i]*(sum_{N+(i)} h1s[s]) + b1 )   (fp32)
//   h2p[i]  = inv[i] * (agg1 @ W2')[i]              (bf16)
//   out     = log_softmax( inv[i]*(sum_{N+(i)} h2p[s]) + b' )
// Assumes n <= 65536 (src packs into 16 bits; bucket id = dst>>8 < 256).

#define CIN  128
#define CHID 128
#define COUT 64
#define BINCHUNK 4096

static __device__ __forceinline__ unsigned short f2bf(float f) {
    unsigned int u = __float_as_uint(f);
    unsigned int r = (u + 0x7fffu + ((u >> 16) & 1u)) >> 16;  // RNE
    return (unsigned short)r;
}
static __device__ __forceinline__ float bf2f(unsigned short v) {
    return __uint_as_float(((unsigned int)v) << 16);
}

// ---------------- pass A: coarse bucket histogram ----------------
__global__ __launch_bounds__(256) void bucket_count_kernel(const int* __restrict__ dst,
                                                           int* __restrict__ bcnt, int E) {
    __shared__ int h[256];
    int t = threadIdx.x;
    h[t] = 0;
    __syncthreads();
    for (int e = blockIdx.x * 256 + t; e < E; e += gridDim.x * 256)
        atomicAdd(&h[dst[e] >> 8], 1);
    __syncthreads();
    int c = h[t];
    if (c) atomicAdd(&bcnt[t], c);
}

// ---------------- pass B: 1-WG exclusive scan of 256 bucket counts ----------------
__global__ __launch_bounds__(256) void bucket_scan_kernel(const int* __restrict__ bcnt,
                                                          int* __restrict__ bbase,
                                                          int* __restrict__ bcursor) {
    __shared__ int s[256];
    int t = threadIdx.x;
    int v = bcnt[t];
    s[t] = v;
    __syncthreads();
    for (int off = 1; off < 256; off <<= 1) {
        int u = (t >= off) ? s[t - off] : 0;
        __syncthreads();
        s[t] += u;
        __syncthreads();
    }
    int ex = s[t] - v;
    bbase[t] = ex;
    bcursor[t] = ex;
}

// ---------------- pass C: bin edges into bucket regions (WG-exclusive sub-regions) ----
__global__ __launch_bounds__(256) void bin_kernel(const int* __restrict__ src,
                                                  const int* __restrict__ dst,
                                                  int* __restrict__ bcursor,
                                                  unsigned int* __restrict__ binned, int E) {
    __shared__ int h[256];     // per-bucket count for this WG's chunk, then local cursor
    __shared__ int base[256];  // global base of this WG's sub-region per bucket
    int t = threadIdx.x;
    h[t] = 0;
    __syncthreads();
    int e0 = blockIdx.x * BINCHUNK;
    int e1 = e0 + BINCHUNK; if (e1 > E) e1 = E;
    // phase 1: count
    for (int e = e0 + t; e < e1; e += 256)
        atomicAdd(&h[dst[e] >> 8], 1);
    __syncthreads();
    // phase 2: reserve global sub-region per bucket
    int c = h[t];
    base[t] = c ? atomicAdd(&bcursor[t], c) : 0;
    __syncthreads();
    h[t] = 0;  // reuse as local cursor
    __syncthreads();
    // phase 3: scatter packed entries
    for (int e = e0 + t; e < e1; e += 256) {
        int d = dst[e];
        int b = d >> 8;
        int pos = base[b] + atomicAdd(&h[b], 1);
        binned[pos] = (unsigned int)src[e] | (((unsigned int)d & 255u) << 16);
    }
}

// ---------------- pass D: per-bucket CSR build (deg->inv, rowptr, ebuf) ----------------
__global__ __launch_bounds__(256) void csr_kernel(const unsigned int* __restrict__ binned,
                                                  const int* __restrict__ bbase,
                                                  const int* __restrict__ bcnt,
                                                  int* __restrict__ rowptr,
                                                  float* __restrict__ inv,
                                                  int* __restrict__ ebuf, int n, int E) {
    __shared__ int h[256];  // per-dst_local hist, later cursor
    __shared__ int s[256];  // scan buffer
    int b = blockIdx.x;
    int t = threadIdx.x;
    int base = bbase[b];
    int cnt  = bcnt[b];
    h[t] = 0;
    __syncthreads();
    // phase 1: per-dst hist
    for (int i = t; i < cnt; i += 256)
        atomicAdd(&h[binned[base + i] >> 16], 1);
    __syncthreads();
    int myc = h[t];
    // phase 2: exclusive scan
    s[t] = myc;
    __syncthreads();
    for (int off = 1; off < 256; off <<= 1) {
        int u = (t >= off) ? s[t - off] : 0;
        __syncthreads();
        s[t] += u;
        __syncthreads();
    }
    int excl = s[t] - myc;
    // phase 3: rowptr + inv, init cursors
    int node = (b << 8) + t;
    if (node < n) {
        rowptr[node] = base + excl;
        inv[node] = rsqrtf((float)(myc + 1));  // +1: self-loop
    }
    if (b == 0 && t == 0) rowptr[n] = E;
    __syncthreads();
    h[t] = base + excl;  // cursor
    __syncthreads();
    // phase 4: scatter src ids (region written only by this WG -> stays in one L2)
    for (int i = t; i < cnt; i += 256) {
        unsigned int v = binned[base + i];
        int pos = atomicAdd(&h[v >> 16], 1);
        ebuf[pos] = (int)(v & 0xffffu);
    }
}

// ---------------- W2' = W2 @ Wsum ; b' = b2 @ Wsum + linb ----------------
__global__ __launch_bounds__(COUT) void w2p_kernel(const float* __restrict__ W2,
                                                   const float* __restrict__ b2,
                                                   const float* __restrict__ linW,
                                                   const float* __restrict__ linb,
                                                   float* __restrict__ W2p,
                                                   float* __restrict__ bp) {
    int r = blockIdx.x;   // 0..128
    int j = threadIdx.x;  // 0..63
    float acc = 0.f;
    if (r < CHID) {
#pragma unroll 8
        for (int k = 0; k < COUT; ++k) {
            float ws = linW[k * COUT + j] + linW[(k + COUT) * COUT + j];
            acc = fmaf(W2[r * COUT + k], ws, acc);
        }
        W2p[r * COUT + j] = acc;
    } else {
#pragma unroll 8
        for (int k = 0; k < COUT; ++k) {
            float ws = linW[k * COUT + j] + linW[(k + COUT) * COUT + j];
            acc = fmaf(b2[k], ws, acc);
        }
        bp[j] = acc + linb[j];
    }
}

// ---------------- GEMM: H[i] = inv[i] * (X @ W)[i], bf16 output ----------------
template <int K, int NOUT, int R>
__global__ void gemm_rows_bf16(const float* __restrict__ X, const float* __restrict__ W,
                               const float* __restrict__ inv, unsigned short* __restrict__ H,
                               int n) {
    __shared__ float xs[R][K];
    int j = threadIdx.x;
    int n0 = blockIdx.x * R;
    constexpr int NF4 = R * K / 4;
    const float4* X4 = (const float4*)(X + (size_t)n0 * K);
    for (int t = j; t < NF4; t += NOUT) {
        int r = t / (K / 4);
        float4 v = (n0 + r < n) ? X4[t] : make_float4(0.f, 0.f, 0.f, 0.f);
        ((float4*)xs)[t] = v;
    }
    __syncthreads();
    float acc[R];
#pragma unroll
    for (int r = 0; r < R; ++r) acc[r] = 0.f;
    for (int k4 = 0; k4 < K / 4; ++k4) {
        float w0 = W[(k4 * 4 + 0) * NOUT + j];
        float w1 = W[(k4 * 4 + 1) * NOUT + j];
        float w2 = W[(k4 * 4 + 2) * NOUT + j];
        float w3 = W[(k4 * 4 + 3) * NOUT + j];
#pragma unroll
        for (int r = 0; r < R; ++r) {
            float4 xv = ((const float4*)xs[r])[k4];
            acc[r] = fmaf(xv.x, w0, acc[r]);
            acc[r] = fmaf(xv.y, w1, acc[r]);
            acc[r] = fmaf(xv.z, w2, acc[r]);
            acc[r] = fmaf(xv.w, w3, acc[r]);
        }
    }
#pragma unroll
    for (int r = 0; r < R; ++r)
        if (n0 + r < n) H[(size_t)(n0 + r) * NOUT + j] = f2bf(acc[r] * inv[n0 + r]);
}

// ---------------- layer-1 aggregate (C=128 bf16): wave/node, scalar edge walk ----
__global__ void agg1_kernel(const unsigned int* __restrict__ Hs, const int* __restrict__ ebuf,
                            const int* __restrict__ rowptr, const float* __restrict__ inv,
                            const float* __restrict__ bias, float* __restrict__ outp, int n) {
    int node = __builtin_amdgcn_readfirstlane(blockIdx.x * 4 + (threadIdx.x >> 6));
    int lane = threadIdx.x & 63;
    if (node >= n) return;
    int beg = rowptr[node], end = rowptr[node + 1];  // uniform addr -> s_load
    float ax = 0.f, ay = 0.f;
#pragma unroll 4
    for (int k = beg; k < end; ++k) {
        int s = ebuf[k];                             // uniform addr -> s_load
        unsigned int u = Hs[(size_t)s * 64 + lane];  // sgpr base + lane offset
        ax += __uint_as_float(u << 16);
        ay += __uint_as_float(u & 0xffff0000u);
    }
    {   // self-loop term
        unsigned int u = Hs[(size_t)node * 64 + lane];
        ax += __uint_as_float(u << 16);
        ay += __uint_as_float(u & 0xffff0000u);
    }
    float wd = inv[node];
    float2 bv = ((const float2*)bias)[lane];
    float ox = fmaxf(fmaf(wd, ax, bv.x), 0.f);
    float oy = fmaxf(fmaf(wd, ay, bv.y), 0.f);
    ((float2*)outp)[(size_t)node * 64 + lane] = make_float2(ox, oy);
}

// ---------------- layer-2 aggregate + bias + log_softmax (projection pre-folded) ----
__global__ void agg2_final_kernel(const unsigned short* __restrict__ Hs,
                                  const int* __restrict__ ebuf, const int* __restrict__ rowptr,
                                  const float* __restrict__ inv, const float* __restrict__ bp,
                                  float* __restrict__ outp, int n) {
    int node = __builtin_amdgcn_readfirstlane(blockIdx.x * 4 + (threadIdx.x >> 6));
    int lane = threadIdx.x & 63;
    if (node >= n) return;
    int beg = rowptr[node], end = rowptr[node + 1];  // uniform -> s_load
    float acc = 0.f;
#pragma unroll 4
    for (int k = beg; k < end; ++k) {
        int s = ebuf[k];                             // uniform -> s_load
        acc += bf2f(Hs[(size_t)s * 64 + lane]);
    }
    acc += bf2f(Hs[(size_t)node * 64 + lane]);       // self-loop
    float fo = fmaf(inv[node], acc, bp[lane]);
    // log_softmax across the wave
    float mx = fo;
#pragma unroll
    for (int off = 32; off >= 1; off >>= 1) mx = fmaxf(mx, __shfl_xor(mx, off, 64));
    float ex = expf(fo - mx);
    float s = ex;
#pragma unroll
    for (int off = 32; off >= 1; off >>= 1) s += __shfl_xor(s, off, 64);
    outp[(size_t)node * COUT + lane] = fo - mx - logf(s);
}

static inline size_t align16(size_t x) { return (x + 15) & ~(size_t)15; }

extern "C" void kernel_launch(void* const* d_in, const int* in_sizes, int n_in,
                              void* d_out, int out_size, void* d_ws, size_t ws_size,
                              hipStream_t stream) {
    const float* x    = (const float*)d_in[0];
    const int*   eidx = (const int*)d_in[1];
    const float* W1   = (const float*)d_in[2];
    const float* b1   = (const float*)d_in[3];
    const float* W2   = (const float*)d_in[4];
    const float* b2   = (const float*)d_in[5];
    const float* linW = (const float*)d_in[6];
    const float* linb = (const float*)d_in[7];
    float* out = (float*)d_out;

    const int n = in_sizes[0] / CIN;   // 50000
    const int E = in_sizes[1] / 2;     // 800000
    const int* src = eidx;
    const int* dst = eidx + E;
    const int NBKT = (n + 255) >> 8;   // 196

    // ---- workspace carve-up
    char* ws = (char*)d_ws;
    size_t off = 0;
    int*   rowptr  = (int*)(ws + off);   off = align16(off + (size_t)(n + 1) * 4);
    float* inv     = (float*)(ws + off); off = align16(off + (size_t)n * 4);
    int*   bcnt    = (int*)(ws + off);   off = align16(off + 256 * 4);
    int*   bbase   = (int*)(ws + off);   off = align16(off + 256 * 4);
    int*   bcursor = (int*)(ws + off);   off = align16(off + 256 * 4);
    float* W2p     = (float*)(ws + off); off = align16(off + (size_t)CHID * COUT * 4);
    float* bp      = (float*)(ws + off); off = align16(off + (size_t)COUT * 4);
    unsigned int* binned = (unsigned int*)(ws + off); off = align16(off + (size_t)E * 4);
    int*   ebuf    = (int*)(ws + off);   off = align16(off + (size_t)E * 4);
    unsigned short* h1s = (unsigned short*)(ws + off); off = align16(off + (size_t)n * CHID * 2);
    float* agg1    = (float*)(ws + off); off = align16(off + (size_t)n * CHID * 4);
    unsigned short* h2p = (unsigned short*)(ws + off); off = align16(off + (size_t)n * COUT * 2);

    hipMemsetAsync(bcnt, 0, 256 * 4, stream);

    // ---- CSR build: count -> scan -> bin -> per-bucket CSR
    bucket_count_kernel<<<256, 256, 0, stream>>>(dst, bcnt, E);
    bucket_scan_kernel<<<1, 256, 0, stream>>>(bcnt, bbase, bcursor);
    bin_kernel<<<(E + BINCHUNK - 1) / BINCHUNK, 256, 0, stream>>>(src, dst, bcursor, binned, E);
    csr_kernel<<<NBKT, 256, 0, stream>>>(binned, bbase, bcnt, rowptr, inv, ebuf, n, E);

    // ---- weight folding
    w2p_kernel<<<CHID + 1, COUT, 0, stream>>>(W2, b2, linW, linb, W2p, bp);

    // ---- layer 1
    gemm_rows_bf16<CIN, CHID, 16><<<(n + 15) / 16, CHID, 0, stream>>>(x, W1, inv, h1s, n);
    agg1_kernel<<<(n + 3) / 4, 256, 0, stream>>>((const unsigned int*)h1s, ebuf, rowptr, inv, b1, agg1, n);

    // ---- layer 2 (projection pre-folded into W2p) + final
    gemm_rows_bf16<CHID, COUT, 16><<<(n + 15) / 16, COUT, 0, stream>>>(agg1, W2p, inv, h2p, n);
    agg2_final_kernel<<<(n + 3) / 4, 256, 0, stream>>>(h2p, ebuf, rowptr, inv, bp, out, n);
}

// Round 8
// 238.834 us; speedup vs baseline: 1.4084x; 1.0997x over previous
//
#include <hip/hip_runtime.h>

// GCN forward: bucket-sort CSR + MFMA GEMMs (bf16 in, fp32 accum) + scalar-walk
// gather aggregation. x1 == x2 (dropout identity) => single branch; output
// projection folded into layer-2 weights:
//   W2' = W2 @ (linW_top + linW_bot),  b' = b2 @ (linW_top+linW_bot) + linb
//   h1s[i]  = inv[i] * (x @ W1)[i]                       (bf16, MFMA)
//   agg1[i] = relu( inv[i]*(sum_{N+(i)} h1s[s]) + b1 )   (bf16 out)
//   h2p[i]  = inv[i] * (agg1 @ W2')[i]                   (bf16, MFMA)
//   out     = log_softmax( inv[i]*(sum_{N+(i)} h2p[s]) + b' )
// Assumes n <= 65536 (src packs in 16 bits), n % 16 == 0 layout-wise.

#define CIN  128
#define CHID 128
#define COUT 64
#define BINCHUNK 4096

typedef short v8s __attribute__((ext_vector_type(8)));
typedef float v4f __attribute__((ext_vector_type(4)));

static __device__ __forceinline__ unsigned short f2bf(float f) {
    unsigned int u = __float_as_uint(f);
    unsigned int r = (u + 0x7fffu + ((u >> 16) & 1u)) >> 16;  // RNE
    return (unsigned short)r;
}
static __device__ __forceinline__ float bf2f(unsigned short v) {
    return __uint_as_float(((unsigned int)v) << 16);
}

// ---------------- pass A: coarse bucket histogram ----------------
__global__ __launch_bounds__(256) void bucket_count_kernel(const int* __restrict__ dst,
                                                           int* __restrict__ bcnt, int E) {
    __shared__ int h[256];
    int t = threadIdx.x;
    h[t] = 0;
    __syncthreads();
    for (int e = blockIdx.x * 256 + t; e < E; e += gridDim.x * 256)
        atomicAdd(&h[dst[e] >> 8], 1);
    __syncthreads();
    int c = h[t];
    if (c) atomicAdd(&bcnt[t], c);
}

// ---------------- pass B: 1-WG exclusive scan of 256 bucket counts ----------------
__global__ __launch_bounds__(256) void bucket_scan_kernel(const int* __restrict__ bcnt,
                                                          int* __restrict__ bbase,
                                                          int* __restrict__ bcursor) {
    __shared__ int s[256];
    int t = threadIdx.x;
    int v = bcnt[t];
    s[t] = v;
    __syncthreads();
    for (int off = 1; off < 256; off <<= 1) {
        int u = (t >= off) ? s[t - off] : 0;
        __syncthreads();
        s[t] += u;
        __syncthreads();
    }
    int ex = s[t] - v;
    bbase[t] = ex;
    bcursor[t] = ex;
}

// ---------------- pass C: bin edges into bucket regions ----------------
__global__ __launch_bounds__(256) void bin_kernel(const int* __restrict__ src,
                                                  const int* __restrict__ dst,
                                                  int* __restrict__ bcursor,
                                                  unsigned int* __restrict__ binned, int E) {
    __shared__ int h[256];
    __shared__ int base[256];
    int t = threadIdx.x;
    h[t] = 0;
    __syncthreads();
    int e0 = blockIdx.x * BINCHUNK;
    int e1 = e0 + BINCHUNK; if (e1 > E) e1 = E;
    for (int e = e0 + t; e < e1; e += 256)
        atomicAdd(&h[dst[e] >> 8], 1);
    __syncthreads();
    int c = h[t];
    base[t] = c ? atomicAdd(&bcursor[t], c) : 0;
    __syncthreads();
    h[t] = 0;
    __syncthreads();
    for (int e = e0 + t; e < e1; e += 256) {
        int d = dst[e];
        int b = d >> 8;
        int pos = base[b] + atomicAdd(&h[b], 1);
        binned[pos] = (unsigned int)src[e] | (((unsigned int)d & 255u) << 16);
    }
}

// ---------------- pass D: per-bucket CSR build ----------------
__global__ __launch_bounds__(256) void csr_kernel(const unsigned int* __restrict__ binned,
                                                  const int* __restrict__ bbase,
                                                  const int* __restrict__ bcnt,
                                                  int* __restrict__ rowptr,
                                                  float* __restrict__ inv,
                                                  int* __restrict__ ebuf, int n, int E) {
    __shared__ int h[256];
    __shared__ int s[256];
    int b = blockIdx.x;
    int t = threadIdx.x;
    int base = bbase[b];
    int cnt  = bcnt[b];
    h[t] = 0;
    __syncthreads();
    for (int i = t; i < cnt; i += 256)
        atomicAdd(&h[binned[base + i] >> 16], 1);
    __syncthreads();
    int myc = h[t];
    s[t] = myc;
    __syncthreads();
    for (int off = 1; off < 256; off <<= 1) {
        int u = (t >= off) ? s[t - off] : 0;
        __syncthreads();
        s[t] += u;
        __syncthreads();
    }
    int excl = s[t] - myc;
    int node = (b << 8) + t;
    if (node < n) {
        rowptr[node] = base + excl;
        inv[node] = rsqrtf((float)(myc + 1));  // +1: self-loop
    }
    if (b == 0 && t == 0) rowptr[n] = E;
    __syncthreads();
    h[t] = base + excl;
    __syncthreads();
    for (int i = t; i < cnt; i += 256) {
        unsigned int v = binned[base + i];
        int pos = atomicAdd(&h[v >> 16], 1);
        ebuf[pos] = (int)(v & 0xffffu);
    }
}

// ---------------- Wt1[j][k] = bf16(W1[k][j]) ----------------
__global__ __launch_bounds__(256) void wt1_kernel(const float* __restrict__ W1,
                                                  unsigned short* __restrict__ Wt1) {
    int i = blockIdx.x * 256 + threadIdx.x;  // over 128*128
    if (i >= CHID * CIN) return;
    int j = i >> 7, k = i & 127;
    Wt1[j * CIN + k] = f2bf(W1[k * CHID + j]);
}

// ---------------- Wt2[j][k] = bf16( (W2 @ Wsum)[k][j] ) ; bp = b2@Wsum + linb ----
__global__ __launch_bounds__(COUT) void w2p_kernel(const float* __restrict__ W2,
                                                   const float* __restrict__ b2,
                                                   const float* __restrict__ linW,
                                                   const float* __restrict__ linb,
                                                   unsigned short* __restrict__ Wt2,
                                                   float* __restrict__ bp) {
    int r = blockIdx.x;   // 0..128 (k-dim of layer-2 GEMM)
    int j = threadIdx.x;  // 0..63
    float acc = 0.f;
    if (r < CHID) {
#pragma unroll 8
        for (int k = 0; k < COUT; ++k) {
            float ws = linW[k * COUT + j] + linW[(k + COUT) * COUT + j];
            acc = fmaf(W2[r * COUT + k], ws, acc);
        }
        Wt2[j * CHID + r] = f2bf(acc);       // transposed, bf16
    } else {
#pragma unroll 8
        for (int k = 0; k < COUT; ++k) {
            float ws = linW[k * COUT + j] + linW[(k + COUT) * COUT + j];
            acc = fmaf(b2[k], ws, acc);
        }
        bp[j] = acc + linb[j];
    }
}

// ---------------- MFMA GEMM: H[i] = inv[i] * (A @ Wt^T)[i], bf16 out ----------
// K=128. One wave = 16 rows x NOUT cols = 4 k-chunks x (NOUT/16) mfma_16x16x32.
// A: fp32 (A_BF16=false, converted in-kernel) or bf16 row-major.
// Wt: bf16 [NOUT][128] (n-major) -> B frag is one 16B load per (ct,kc).
template <int NOUT, bool A_BF16>
__global__ __launch_bounds__(256) void gemm_mfma(const void* __restrict__ Aptr,
                                                 const unsigned short* __restrict__ Wt,
                                                 const float* __restrict__ inv,
                                                 unsigned short* __restrict__ H, int n) {
    constexpr int NCT = NOUT / 16;
    int lane = threadIdx.x & 63;
    int wave = threadIdx.x >> 6;
    int quad = lane >> 4, r16 = lane & 15;
    int row0 = (blockIdx.x * 4 + wave) * 16;
    if (row0 >= n) return;
    int arow = row0 + r16;
    if (arow >= n) arow = n - 1;  // clamp (safe: result masked by orow<n)

    v4f acc[NCT];
#pragma unroll
    for (int c = 0; c < NCT; ++c) acc[c] = (v4f){0.f, 0.f, 0.f, 0.f};

#pragma unroll
    for (int kc = 0; kc < 4; ++kc) {
        v8s af;
        if (A_BF16) {
            const unsigned short* A = (const unsigned short*)Aptr;
            af = *(const v8s*)(A + (size_t)arow * 128 + kc * 32 + quad * 8);
        } else {
            const float* A = (const float*)Aptr;
            const float4* ap = (const float4*)(A + (size_t)arow * 128 + kc * 32 + quad * 8);
            float4 a0 = ap[0], a1 = ap[1];
            af[0] = (short)f2bf(a0.x); af[1] = (short)f2bf(a0.y);
            af[2] = (short)f2bf(a0.z); af[3] = (short)f2bf(a0.w);
            af[4] = (short)f2bf(a1.x); af[5] = (short)f2bf(a1.y);
            af[6] = (short)f2bf(a1.z); af[7] = (short)f2bf(a1.w);
        }
#pragma unroll
        for (int ct = 0; ct < NCT; ++ct) {
            v8s bf = *(const v8s*)(Wt + (size_t)(ct * 16 + r16) * 128 + kc * 32 + quad * 8);
            acc[ct] = __builtin_amdgcn_mfma_f32_16x16x32_bf16(af, bf, acc[ct], 0, 0, 0);
        }
    }

    // epilogue: row = quad*4 + i (C/D layout), col = ct*16 + r16
    float4 iv = ((const float4*)(inv + row0))[quad];
#pragma unroll
    for (int ct = 0; ct < NCT; ++ct) {
#pragma unroll
        for (int i = 0; i < 4; ++i) {
            int orow = row0 + quad * 4 + i;
            if (orow < n) {
                float sc = (i == 0) ? iv.x : (i == 1) ? iv.y : (i == 2) ? iv.z : iv.w;
                H[(size_t)orow * NOUT + ct * 16 + r16] = f2bf(acc[ct][i] * sc);
            }
        }
    }
}

// ---------------- layer-1 aggregate (C=128 bf16): wave/node, scalar edge walk ----
// Output bf16-packed (uint = 2 channels/lane).
__global__ void agg1_kernel(const unsigned int* __restrict__ Hs, const int* __restrict__ ebuf,
                            const int* __restrict__ rowptr, const float* __restrict__ inv,
                            const float* __restrict__ bias, unsigned int* __restrict__ outp,
                            int n) {
    int node = __builtin_amdgcn_readfirstlane(blockIdx.x * 4 + (threadIdx.x >> 6));
    int lane = threadIdx.x & 63;
    if (node >= n) return;
    int beg = rowptr[node], end = rowptr[node + 1];  // uniform addr -> s_load
    float ax = 0.f, ay = 0.f;
#pragma unroll 4
    for (int k = beg; k < end; ++k) {
        int s = ebuf[k];                             // uniform addr -> s_load
        unsigned int u = Hs[(size_t)s * 64 + lane];
        ax += __uint_as_float(u << 16);
        ay += __uint_as_float(u & 0xffff0000u);
    }
    {   // self-loop term
        unsigned int u = Hs[(size_t)node * 64 + lane];
        ax += __uint_as_float(u << 16);
        ay += __uint_as_float(u & 0xffff0000u);
    }
    float wd = inv[node];
    float2 bv = ((const float2*)bias)[lane];
    float ox = fmaxf(fmaf(wd, ax, bv.x), 0.f);
    float oy = fmaxf(fmaf(wd, ay, bv.y), 0.f);
    outp[(size_t)node * 64 + lane] =
        (unsigned int)f2bf(ox) | ((unsigned int)f2bf(oy) << 16);
}

// ---------------- layer-2 aggregate + bias + log_softmax ----------------
__global__ void agg2_final_kernel(const unsigned short* __restrict__ Hs,
                                  const int* __restrict__ ebuf, const int* __restrict__ rowptr,
                                  const float* __restrict__ inv, const float* __restrict__ bp,
                                  float* __restrict__ outp, int n) {
    int node = __builtin_amdgcn_readfirstlane(blockIdx.x * 4 + (threadIdx.x >> 6));
    int lane = threadIdx.x & 63;
    if (node >= n) return;
    int beg = rowptr[node], end = rowptr[node + 1];
    float acc = 0.f;
#pragma unroll 4
    for (int k = beg; k < end; ++k) {
        int s = ebuf[k];
        acc += bf2f(Hs[(size_t)s * 64 + lane]);
    }
    acc += bf2f(Hs[(size_t)node * 64 + lane]);  // self-loop
    float fo = fmaf(inv[node], acc, bp[lane]);
    float mx = fo;
#pragma unroll
    for (int off = 32; off >= 1; off >>= 1) mx = fmaxf(mx, __shfl_xor(mx, off, 64));
    float ex = expf(fo - mx);
    float s = ex;
#pragma unroll
    for (int off = 32; off >= 1; off >>= 1) s += __shfl_xor(s, off, 64);
    outp[(size_t)node * COUT + lane] = fo - mx - logf(s);
}

static inline size_t align16(size_t x) { return (x + 15) & ~(size_t)15; }

extern "C" void kernel_launch(void* const* d_in, const int* in_sizes, int n_in,
                              void* d_out, int out_size, void* d_ws, size_t ws_size,
                              hipStream_t stream) {
    const float* x    = (const float*)d_in[0];
    const int*   eidx = (const int*)d_in[1];
    const float* W1   = (const float*)d_in[2];
    const float* b1   = (const float*)d_in[3];
    const float* W2   = (const float*)d_in[4];
    const float* b2   = (const float*)d_in[5];
    const float* linW = (const float*)d_in[6];
    const float* linb = (const float*)d_in[7];
    float* out = (float*)d_out;

    const int n = in_sizes[0] / CIN;   // 50000
    const int E = in_sizes[1] / 2;     // 800000
    const int* src = eidx;
    const int* dst = eidx + E;
    const int NBKT = (n + 255) >> 8;   // 196

    // ---- workspace carve-up
    char* ws = (char*)d_ws;
    size_t off = 0;
    int*   rowptr  = (int*)(ws + off);   off = align16(off + (size_t)(n + 1) * 4);
    float* inv     = (float*)(ws + off); off = align16(off + (size_t)n * 4);
    int*   bcnt    = (int*)(ws + off);   off = align16(off + 256 * 4);
    int*   bbase   = (int*)(ws + off);   off = align16(off + 256 * 4);
    int*   bcursor = (int*)(ws + off);   off = align16(off + 256 * 4);
    unsigned short* Wt1 = (unsigned short*)(ws + off); off = align16(off + (size_t)CHID * CIN * 2);
    unsigned short* Wt2 = (unsigned short*)(ws + off); off = align16(off + (size_t)COUT * CHID * 2);
    float* bp      = (float*)(ws + off); off = align16(off + (size_t)COUT * 4);
    unsigned int* binned = (unsigned int*)(ws + off); off = align16(off + (size_t)E * 4);
    int*   ebuf    = (int*)(ws + off);   off = align16(off + (size_t)E * 4);
    unsigned short* h1s   = (unsigned short*)(ws + off); off = align16(off + (size_t)n * CHID * 2);
    unsigned short* agg1b = (unsigned short*)(ws + off); off = align16(off + (size_t)n * CHID * 2);
    unsigned short* h2p   = (unsigned short*)(ws + off); off = align16(off + (size_t)n * COUT * 2);

    hipMemsetAsync(bcnt, 0, 256 * 4, stream);

    // ---- CSR build: count -> scan -> bin -> per-bucket CSR
    bucket_count_kernel<<<256, 256, 0, stream>>>(dst, bcnt, E);
    bucket_scan_kernel<<<1, 256, 0, stream>>>(bcnt, bbase, bcursor);
    bin_kernel<<<(E + BINCHUNK - 1) / BINCHUNK, 256, 0, stream>>>(src, dst, bcursor, binned, E);
    csr_kernel<<<NBKT, 256, 0, stream>>>(binned, bbase, bcnt, rowptr, inv, ebuf, n, E);

    // ---- weight prep (bf16, transposed; projection folded into Wt2)
    wt1_kernel<<<(CHID * CIN + 255) / 256, 256, 0, stream>>>(W1, Wt1);
    w2p_kernel<<<CHID + 1, COUT, 0, stream>>>(W2, b2, linW, linb, Wt2, bp);

    // ---- layer 1: MFMA GEMM + gather-aggregate
    gemm_mfma<CHID, false><<<(n + 63) / 64, 256, 0, stream>>>(x, Wt1, inv, h1s, n);
    agg1_kernel<<<(n + 3) / 4, 256, 0, stream>>>((const unsigned int*)h1s, ebuf, rowptr, inv, b1,
                                                 (unsigned int*)agg1b, n);

    // ---- layer 2: MFMA GEMM (bf16 A) + final
    gemm_mfma<COUT, true><<<(n + 63) / 64, 256, 0, stream>>>(agg1b, Wt2, inv, h2p, n);
    agg2_final_kernel<<<(n + 3) / 4, 256, 0, stream>>>(h2p, ebuf, rowptr, inv, bp, out, n);
}